// Round 1
// baseline (3679.066 us; speedup 1.0000x reference)
//
#include <hip/hip_runtime.h>
#include <hip/hip_bf16.h>

static constexpr int NN = 50000;
static constexpr int NE = 800000;
static constexpr float BN_EPS = 1e-5f;

// ---------------------------------------------------------------------------
// Scatter: agg[dst[e]] += h[src[e]]  (d channels, DQ = d/4 float4 per edge)
// ---------------------------------------------------------------------------
template<int DQ>
__global__ __launch_bounds__(256) void scatter_kernel(
    const float* __restrict__ h, const int* __restrict__ src,
    const int* __restrict__ dst, float* __restrict__ agg)
{
    int idx = blockIdx.x * 256 + threadIdx.x;
    if (idx >= NE * DQ) return;
    int e = idx / DQ;           // DQ is power of two -> shift
    int q = idx - e * DQ;
    int s = src[e];
    int d = dst[e];
    float4 v = reinterpret_cast<const float4*>(h + (size_t)s * (DQ * 4))[q];
    float* a = agg + (size_t)d * (DQ * 4) + q * 4;
    atomicAdd(a + 0, v.x);
    atomicAdd(a + 1, v.y);
    atomicAdd(a + 2, v.z);
    atomicAdd(a + 3, v.w);
}

// ---------------------------------------------------------------------------
// Fused MLP: z = relu((hin+agg) @ W1 + b1) @ W2 + b2, plus BN-stat partials
// One block = 32 rows, 256 threads. Thread computes 2 rows x 4 cols.
// ---------------------------------------------------------------------------
template<int D>
__global__ __launch_bounds__(256) void mlp_kernel(
    const float* __restrict__ hin, const float* __restrict__ agg,
    const float* __restrict__ W1, const float* __restrict__ b1,
    const float* __restrict__ W2, const float* __restrict__ b2,
    float* __restrict__ zout, float* __restrict__ gsum, float* __restrict__ gsq)
{
    constexpr int ROWS = 32;
    __shared__ float Xs[ROWS][D + 1];
    __shared__ float W1s[D][64];
    __shared__ float W2s[64][64];
    __shared__ float Ys[ROWS][65];
    __shared__ float b1s[64], b2s[64];
    __shared__ float lsum[64], lsq[64];

    const int t = threadIdx.x;
    const int rowbase = blockIdx.x * ROWS;

    // stage weights + biases
    {
        const float4* w1v = reinterpret_cast<const float4*>(W1);
        float4* w1sv = reinterpret_cast<float4*>(&W1s[0][0]);
        for (int i = t; i < D * 16; i += 256) w1sv[i] = w1v[i];
        const float4* w2v = reinterpret_cast<const float4*>(W2);
        float4* w2sv = reinterpret_cast<float4*>(&W2s[0][0]);
        for (int i = t; i < 64 * 16; i += 256) w2sv[i] = w2v[i];
        if (t < 64) { b1s[t] = b1[t]; b2s[t] = b2[t]; lsum[t] = 0.f; lsq[t] = 0.f; }
    }

    // stage X = hin + agg
    {
        constexpr int QPR = D / 4;        // float4 per row
        constexpr int RPI = 256 / QPR;    // rows per iteration
        int q = t % QPR, rr = t / QPR;
        for (int i = 0; i < ROWS; i += RPI) {
            int r = i + rr;
            int gr = rowbase + r;
            float4 v;
            if (gr < NN) {
                float4 a = reinterpret_cast<const float4*>(hin + (size_t)gr * D)[q];
                float4 b = reinterpret_cast<const float4*>(agg + (size_t)gr * D)[q];
                v = make_float4(a.x + b.x, a.y + b.y, a.z + b.z, a.w + b.w);
            } else {
                v = make_float4(0.f, 0.f, 0.f, 0.f);
            }
            Xs[r][q * 4 + 0] = v.x; Xs[r][q * 4 + 1] = v.y;
            Xs[r][q * 4 + 2] = v.z; Xs[r][q * 4 + 3] = v.w;
        }
    }
    __syncthreads();

    const int tc = t & 15;
    const int tr = t >> 4;
    const int c0 = tc * 4;
    const int r0 = tr * 2;

    // GEMM1 + relu -> Ys
    {
        float a0x = 0.f, a0y = 0.f, a0z = 0.f, a0w = 0.f;
        float a1x = 0.f, a1y = 0.f, a1z = 0.f, a1w = 0.f;
        for (int k = 0; k < D; ++k) {
            float x0 = Xs[r0][k];
            float x1 = Xs[r0 + 1][k];
            float4 w = *reinterpret_cast<const float4*>(&W1s[k][c0]);
            a0x += x0 * w.x; a0y += x0 * w.y; a0z += x0 * w.z; a0w += x0 * w.w;
            a1x += x1 * w.x; a1y += x1 * w.y; a1z += x1 * w.z; a1w += x1 * w.w;
        }
        Ys[r0][c0 + 0] = fmaxf(a0x + b1s[c0 + 0], 0.f);
        Ys[r0][c0 + 1] = fmaxf(a0y + b1s[c0 + 1], 0.f);
        Ys[r0][c0 + 2] = fmaxf(a0z + b1s[c0 + 2], 0.f);
        Ys[r0][c0 + 3] = fmaxf(a0w + b1s[c0 + 3], 0.f);
        Ys[r0 + 1][c0 + 0] = fmaxf(a1x + b1s[c0 + 0], 0.f);
        Ys[r0 + 1][c0 + 1] = fmaxf(a1y + b1s[c0 + 1], 0.f);
        Ys[r0 + 1][c0 + 2] = fmaxf(a1z + b1s[c0 + 2], 0.f);
        Ys[r0 + 1][c0 + 3] = fmaxf(a1w + b1s[c0 + 3], 0.f);
    }
    __syncthreads();

    // GEMM2 -> z  (+ store + BN stats)
    {
        float a0x = 0.f, a0y = 0.f, a0z = 0.f, a0w = 0.f;
        float a1x = 0.f, a1y = 0.f, a1z = 0.f, a1w = 0.f;
        for (int k = 0; k < 64; ++k) {
            float y0 = Ys[r0][k];
            float y1 = Ys[r0 + 1][k];
            float4 w = *reinterpret_cast<const float4*>(&W2s[k][c0]);
            a0x += y0 * w.x; a0y += y0 * w.y; a0z += y0 * w.z; a0w += y0 * w.w;
            a1x += y1 * w.x; a1y += y1 * w.y; a1z += y1 * w.z; a1w += y1 * w.w;
        }
        float z0[4] = { a0x + b2s[c0 + 0], a0y + b2s[c0 + 1],
                        a0z + b2s[c0 + 2], a0w + b2s[c0 + 3] };
        float z1[4] = { a1x + b2s[c0 + 0], a1y + b2s[c0 + 1],
                        a1z + b2s[c0 + 2], a1w + b2s[c0 + 3] };
        int gr0 = rowbase + r0;
        int gr1 = gr0 + 1;
        bool v0 = gr0 < NN, v1 = gr1 < NN;
        if (v0) *reinterpret_cast<float4*>(zout + (size_t)gr0 * 64 + c0) =
            make_float4(z0[0], z0[1], z0[2], z0[3]);
        if (v1) *reinterpret_cast<float4*>(zout + (size_t)gr1 * 64 + c0) =
            make_float4(z1[0], z1[1], z1[2], z1[3]);

        float s[4], q2[4];
        #pragma unroll
        for (int j = 0; j < 4; ++j) {
            float t0 = v0 ? z0[j] : 0.f;
            float t1 = v1 ? z1[j] : 0.f;
            s[j]  = t0 + t1;
            q2[j] = t0 * t0 + t1 * t1;
        }
        // reduce across the wave's 4 row-groups (lane bits 4,5)
        #pragma unroll
        for (int j = 0; j < 4; ++j) {
            s[j]  += __shfl_xor(s[j], 16);
            s[j]  += __shfl_xor(s[j], 32);
            q2[j] += __shfl_xor(q2[j], 16);
            q2[j] += __shfl_xor(q2[j], 32);
        }
        if ((t & 48) == 0) {
            #pragma unroll
            for (int j = 0; j < 4; ++j) {
                atomicAdd(&lsum[c0 + j], s[j]);
                atomicAdd(&lsq[c0 + j], q2[j]);
            }
        }
    }
    __syncthreads();
    if (t < 64) {
        atomicAdd(&gsum[t], lsum[t]);
        atomicAdd(&gsq[t], lsq[t]);
    }
}

// ---------------------------------------------------------------------------
// Finalize BN stats -> per-channel scale/shift
// ---------------------------------------------------------------------------
__global__ void finalize_kernel(const float* __restrict__ gsum,
                                const float* __restrict__ gsq,
                                const float* __restrict__ gamma,
                                const float* __restrict__ beta,
                                float* __restrict__ scale,
                                float* __restrict__ shift)
{
    int c = threadIdx.x;
    if (c >= 64) return;
    const float invn = 1.f / (float)NN;
    float mean = gsum[c] * invn;
    float var  = gsq[c] * invn - mean * mean;
    float inv  = rsqrtf(var + BN_EPS);
    float sc   = gamma[c] * inv;
    scale[c] = sc;
    shift[c] = beta[c] - mean * sc;
}

// ---------------------------------------------------------------------------
// Normalize + ReLU (elementwise, float4)
// ---------------------------------------------------------------------------
__global__ __launch_bounds__(256) void norm_kernel(
    const float* __restrict__ z, const float* __restrict__ scale,
    const float* __restrict__ shift, float* __restrict__ out)
{
    __shared__ float sc[64], sh[64];
    if (threadIdx.x < 64) {
        sc[threadIdx.x] = scale[threadIdx.x];
        sh[threadIdx.x] = shift[threadIdx.x];
    }
    __syncthreads();
    int idx = blockIdx.x * 256 + threadIdx.x;   // float4 index
    if (idx >= NN * 16) return;
    int c = (idx & 15) * 4;
    float4 v = reinterpret_cast<const float4*>(z)[idx];
    v.x = fmaxf(v.x * sc[c + 0] + sh[c + 0], 0.f);
    v.y = fmaxf(v.y * sc[c + 1] + sh[c + 1], 0.f);
    v.z = fmaxf(v.z * sc[c + 2] + sh[c + 2], 0.f);
    v.w = fmaxf(v.w * sc[c + 3] + sh[c + 3], 0.f);
    reinterpret_cast<float4*>(out)[idx] = v;
}

// ---------------------------------------------------------------------------
extern "C" void kernel_launch(void* const* d_in, const int* in_sizes, int n_in,
                              void* d_out, int out_size, void* d_ws, size_t ws_size,
                              hipStream_t stream)
{
    const float* h    = (const float*)d_in[0];
    const int*   src  = (const int*)d_in[1];
    const int*   dst  = (const int*)d_in[2];
    const float* W1_0 = (const float*)d_in[3];
    const float* b1_0 = (const float*)d_in[4];
    const float* W2_0 = (const float*)d_in[5];
    const float* b2_0 = (const float*)d_in[6];
    const float* g_0  = (const float*)d_in[7];
    const float* be_0 = (const float*)d_in[8];
    const float* W1st = (const float*)d_in[9];
    const float* b1st = (const float*)d_in[10];
    const float* W2st = (const float*)d_in[11];
    const float* b2st = (const float*)d_in[12];
    const float* gst  = (const float*)d_in[13];
    const float* best = (const float*)d_in[14];
    float* out = (float*)d_out;

    float* ws    = (float*)d_ws;
    float* agg   = ws;                              // NN*128 floats
    float* z1    = agg + (size_t)NN * 128;          // NN*64 floats
    float* stats = z1 + (size_t)NN * 64;            // 256 floats
    float* gsum  = stats;
    float* gsq   = stats + 64;
    float* scale = stats + 128;
    float* shift = stats + 192;

    auto run_layer = [&](const float* hin, float* zbuf, int D,
                         const float* W1, const float* b1,
                         const float* W2, const float* b2,
                         const float* gamma, const float* beta) {
        hipMemsetAsync(agg, 0, (size_t)NN * D * sizeof(float), stream);
        hipMemsetAsync(stats, 0, 128 * sizeof(float), stream);
        if (D == 128) {
            int total = NE * 32;
            scatter_kernel<32><<<(total + 255) / 256, 256, 0, stream>>>(hin, src, dst, agg);
            mlp_kernel<128><<<(NN + 31) / 32, 256, 0, stream>>>(
                hin, agg, W1, b1, W2, b2, zbuf, gsum, gsq);
        } else {
            int total = NE * 16;
            scatter_kernel<16><<<(total + 255) / 256, 256, 0, stream>>>(hin, src, dst, agg);
            mlp_kernel<64><<<(NN + 31) / 32, 256, 0, stream>>>(
                hin, agg, W1, b1, W2, b2, zbuf, gsum, gsq);
        }
        finalize_kernel<<<1, 64, 0, stream>>>(gsum, gsq, gamma, beta, scale, shift);
        norm_kernel<<<(NN * 16 + 255) / 256, 256, 0, stream>>>(zbuf, scale, shift, zbuf);
    };

    // L0: input h (d=128) -> z1
    run_layer(h, z1, 128, W1_0, b1_0, W2_0, b2_0, g_0, be_0);
    // L1: z1 -> out
    run_layer(z1, out, 64, W1st + 0 * 4096, b1st + 0 * 64, W2st + 0 * 4096,
              b2st + 0 * 64, gst + 0 * 64, best + 0 * 64);
    // L2: out -> z1
    run_layer(out, z1, 64, W1st + 1 * 4096, b1st + 1 * 64, W2st + 1 * 4096,
              b2st + 1 * 64, gst + 1 * 64, best + 1 * 64);
    // L3: z1 -> out  (final result lands in d_out)
    run_layer(z1, out, 64, W1st + 2 * 4096, b1st + 2 * 64, W2st + 2 * 4096,
              b2st + 2 * 64, gst + 2 * 64, best + 2 * 64);
}

// Round 2
// 1004.760 us; speedup vs baseline: 3.6616x; 3.6616x over previous
//
#include <hip/hip_runtime.h>
#include <hip/hip_bf16.h>

static constexpr int NN = 50000;
static constexpr int NE = 800000;
static constexpr float BN_EPS = 1e-5f;

// ===========================================================================
// CSR build: group edges by dst so aggregation becomes a gather (no fp atomics)
// ===========================================================================
__global__ __launch_bounds__(256) void deg_kernel(const int* __restrict__ dst,
                                                  int* __restrict__ deg)
{
    int e = blockIdx.x * 256 + threadIdx.x;
    if (e < NE) atomicAdd(&deg[dst[e]], 1);
}

__global__ __launch_bounds__(1024) void scan1_kernel(const int* __restrict__ deg,
                                                     int* __restrict__ off,
                                                     int* __restrict__ bsum)
{
    __shared__ int s[1024];
    int t = threadIdx.x;
    int i = blockIdx.x * 1024 + t;
    s[t] = (i < NN) ? deg[i] : 0;
    __syncthreads();
    for (int d = 1; d < 1024; d <<= 1) {
        int x = (t >= d) ? s[t - d] : 0;
        __syncthreads();
        s[t] += x;
        __syncthreads();
    }
    if (i < NN) off[i + 1] = s[t];           // block-local inclusive scan
    if (t == 1023) bsum[blockIdx.x] = s[1023];
}

__global__ void scan2_kernel(int* bsum, int nblk)
{
    if (threadIdx.x == 0 && blockIdx.x == 0) {
        int run = 0;
        for (int i = 0; i < nblk; ++i) { int v = bsum[i]; bsum[i] = run; run += v; }
    }
}

__global__ __launch_bounds__(256) void scan3_kernel(int* __restrict__ off,
                                                    const int* __restrict__ bsum)
{
    int i = blockIdx.x * 256 + threadIdx.x;
    if (i == 0) off[0] = 0;
    if (i < NN) off[i + 1] += bsum[i >> 10];
}

__global__ __launch_bounds__(256) void fill_kernel(const int* __restrict__ src,
                                                   const int* __restrict__ dst,
                                                   int* __restrict__ cursor,
                                                   int* __restrict__ eidx)
{
    int e = blockIdx.x * 256 + threadIdx.x;
    if (e >= NE) return;
    int pos = atomicAdd(&cursor[dst[e]], 1);
    eidx[pos] = src[e];
}

// ===========================================================================
// proj: p = hin @ W1   (no bias; bias added post-aggregation)
// Block = 32 rows, 256 threads; thread computes 2 rows x 4 cols.
// ===========================================================================
template<int D>
__global__ __launch_bounds__(256) void proj_kernel(
    const float* __restrict__ hin, const float* __restrict__ W1,
    float* __restrict__ p)
{
    constexpr int ROWS = 32;
    __shared__ float Xs[ROWS][D + 1];
    __shared__ float W1s[D][64];

    const int t = threadIdx.x;
    const int rowbase = blockIdx.x * ROWS;

    {
        const float4* w1v = reinterpret_cast<const float4*>(W1);
        float4* w1sv = reinterpret_cast<float4*>(&W1s[0][0]);
        for (int i = t; i < D * 16; i += 256) w1sv[i] = w1v[i];
    }
    {
        constexpr int QPR = D / 4;
        constexpr int RPI = 256 / QPR;
        int q = t % QPR, rr = t / QPR;
        for (int i = 0; i < ROWS; i += RPI) {
            int r = i + rr;
            int gr = rowbase + r;
            float4 v = make_float4(0.f, 0.f, 0.f, 0.f);
            if (gr < NN) v = reinterpret_cast<const float4*>(hin + (size_t)gr * D)[q];
            Xs[r][q * 4 + 0] = v.x; Xs[r][q * 4 + 1] = v.y;
            Xs[r][q * 4 + 2] = v.z; Xs[r][q * 4 + 3] = v.w;
        }
    }
    __syncthreads();

    const int tc = t & 15;
    const int tr = t >> 4;
    const int c0 = tc * 4;
    const int r0 = tr * 2;

    float a0x = 0.f, a0y = 0.f, a0z = 0.f, a0w = 0.f;
    float a1x = 0.f, a1y = 0.f, a1z = 0.f, a1w = 0.f;
    for (int k = 0; k < D; ++k) {
        float x0 = Xs[r0][k];
        float x1 = Xs[r0 + 1][k];
        float4 w = *reinterpret_cast<const float4*>(&W1s[k][c0]);
        a0x += x0 * w.x; a0y += x0 * w.y; a0z += x0 * w.z; a0w += x0 * w.w;
        a1x += x1 * w.x; a1y += x1 * w.y; a1z += x1 * w.z; a1w += x1 * w.w;
    }
    int gr0 = rowbase + r0;
    int gr1 = gr0 + 1;
    if (gr0 < NN) reinterpret_cast<float4*>(p + (size_t)gr0 * 64)[tc] =
        make_float4(a0x, a0y, a0z, a0w);
    if (gr1 < NN) reinterpret_cast<float4*>(p + (size_t)gr1 * 64)[tc] =
        make_float4(a1x, a1y, a1z, a1w);
}

// ===========================================================================
// gmlp: Y = relu(p_i + sum_{j in N(i)} p_j + b1); z = Y @ W2 + b2 (+BN stats)
// Block = 32 rows, 256 threads. Gather: 16 threads per row (float4 each).
// ===========================================================================
__global__ __launch_bounds__(256) void gmlp_kernel(
    const float* __restrict__ p, const int* __restrict__ off,
    const int* __restrict__ eidx, const float* __restrict__ b1,
    const float* __restrict__ W2, const float* __restrict__ b2,
    float* __restrict__ zout, float* __restrict__ gsum, float* __restrict__ gsq)
{
    constexpr int ROWS = 32;
    __shared__ float Ys[ROWS][65];
    __shared__ float W2s[64][64];
    __shared__ float b1s[64], b2s[64], lsum[64], lsq[64];

    const int t = threadIdx.x;
    const int rowbase = blockIdx.x * ROWS;

    {
        const float4* w2v = reinterpret_cast<const float4*>(W2);
        float4* w2sv = reinterpret_cast<float4*>(&W2s[0][0]);
        for (int i = t; i < 64 * 16; i += 256) w2sv[i] = w2v[i];
        if (t < 64) { b1s[t] = b1[t]; b2s[t] = b2[t]; lsum[t] = 0.f; lsq[t] = 0.f; }
    }
    __syncthreads();

    // gather + bias + relu -> Ys
    {
        int q = t & 15;      // float4 slot within the 64-wide row
        int rr = t >> 4;     // 16 rows per pass
        for (int i = 0; i < ROWS; i += 16) {
            int r = i + rr;
            int gr = rowbase + r;
            float ax = 0.f, ay = 0.f, az = 0.f, aw = 0.f;
            if (gr < NN) {
                float4 self = reinterpret_cast<const float4*>(p + (size_t)gr * 64)[q];
                ax = self.x; ay = self.y; az = self.z; aw = self.w;
                int beg = off[gr], end = off[gr + 1];
                for (int e = beg; e < end; ++e) {
                    int s = eidx[e];
                    float4 v = reinterpret_cast<const float4*>(p + (size_t)s * 64)[q];
                    ax += v.x; ay += v.y; az += v.z; aw += v.w;
                }
                int c = q * 4;
                ax = fmaxf(ax + b1s[c + 0], 0.f);
                ay = fmaxf(ay + b1s[c + 1], 0.f);
                az = fmaxf(az + b1s[c + 2], 0.f);
                aw = fmaxf(aw + b1s[c + 3], 0.f);
            }
            Ys[r][q * 4 + 0] = ax; Ys[r][q * 4 + 1] = ay;
            Ys[r][q * 4 + 2] = az; Ys[r][q * 4 + 3] = aw;
        }
    }
    __syncthreads();

    const int tc = t & 15;
    const int tr = t >> 4;
    const int c0 = tc * 4;
    const int r0 = tr * 2;

    // GEMM2 -> z (+ store + BN stats)
    float a0x = 0.f, a0y = 0.f, a0z = 0.f, a0w = 0.f;
    float a1x = 0.f, a1y = 0.f, a1z = 0.f, a1w = 0.f;
    for (int k = 0; k < 64; ++k) {
        float y0 = Ys[r0][k];
        float y1 = Ys[r0 + 1][k];
        float4 w = *reinterpret_cast<const float4*>(&W2s[k][c0]);
        a0x += y0 * w.x; a0y += y0 * w.y; a0z += y0 * w.z; a0w += y0 * w.w;
        a1x += y1 * w.x; a1y += y1 * w.y; a1z += y1 * w.z; a1w += y1 * w.w;
    }
    float z0[4] = { a0x + b2s[c0 + 0], a0y + b2s[c0 + 1],
                    a0z + b2s[c0 + 2], a0w + b2s[c0 + 3] };
    float z1[4] = { a1x + b2s[c0 + 0], a1y + b2s[c0 + 1],
                    a1z + b2s[c0 + 2], a1w + b2s[c0 + 3] };
    int gr0 = rowbase + r0;
    int gr1 = gr0 + 1;
    bool v0 = gr0 < NN, v1 = gr1 < NN;
    if (v0) *reinterpret_cast<float4*>(zout + (size_t)gr0 * 64 + c0) =
        make_float4(z0[0], z0[1], z0[2], z0[3]);
    if (v1) *reinterpret_cast<float4*>(zout + (size_t)gr1 * 64 + c0) =
        make_float4(z1[0], z1[1], z1[2], z1[3]);

    float s[4], q2[4];
    #pragma unroll
    for (int j = 0; j < 4; ++j) {
        float t0 = v0 ? z0[j] : 0.f;
        float t1 = v1 ? z1[j] : 0.f;
        s[j]  = t0 + t1;
        q2[j] = t0 * t0 + t1 * t1;
    }
    #pragma unroll
    for (int j = 0; j < 4; ++j) {
        s[j]  += __shfl_xor(s[j], 16);
        s[j]  += __shfl_xor(s[j], 32);
        q2[j] += __shfl_xor(q2[j], 16);
        q2[j] += __shfl_xor(q2[j], 32);
    }
    if ((t & 48) == 0) {
        #pragma unroll
        for (int j = 0; j < 4; ++j) {
            atomicAdd(&lsum[c0 + j], s[j]);
            atomicAdd(&lsq[c0 + j], q2[j]);
        }
    }
    __syncthreads();
    if (t < 64) {
        atomicAdd(&gsum[t], lsum[t]);
        atomicAdd(&gsq[t], lsq[t]);
    }
}

// ===========================================================================
__global__ void finalize_kernel(const float* __restrict__ gsum,
                                const float* __restrict__ gsq,
                                const float* __restrict__ gamma,
                                const float* __restrict__ beta,
                                float* __restrict__ scale,
                                float* __restrict__ shift)
{
    int c = threadIdx.x;
    if (c >= 64) return;
    const float invn = 1.f / (float)NN;
    float mean = gsum[c] * invn;
    float var  = gsq[c] * invn - mean * mean;
    float inv  = rsqrtf(var + BN_EPS);
    float sc   = gamma[c] * inv;
    scale[c] = sc;
    shift[c] = beta[c] - mean * sc;
}

__global__ __launch_bounds__(256) void norm_kernel(
    const float* __restrict__ z, const float* __restrict__ scale,
    const float* __restrict__ shift, float* __restrict__ out)
{
    __shared__ float sc[64], sh[64];
    if (threadIdx.x < 64) {
        sc[threadIdx.x] = scale[threadIdx.x];
        sh[threadIdx.x] = shift[threadIdx.x];
    }
    __syncthreads();
    int idx = blockIdx.x * 256 + threadIdx.x;   // float4 index
    if (idx >= NN * 16) return;
    int c = (idx & 15) * 4;
    float4 v = reinterpret_cast<const float4*>(z)[idx];
    v.x = fmaxf(v.x * sc[c + 0] + sh[c + 0], 0.f);
    v.y = fmaxf(v.y * sc[c + 1] + sh[c + 1], 0.f);
    v.z = fmaxf(v.z * sc[c + 2] + sh[c + 2], 0.f);
    v.w = fmaxf(v.w * sc[c + 3] + sh[c + 3], 0.f);
    reinterpret_cast<float4*>(out)[idx] = v;
}

// ===========================================================================
extern "C" void kernel_launch(void* const* d_in, const int* in_sizes, int n_in,
                              void* d_out, int out_size, void* d_ws, size_t ws_size,
                              hipStream_t stream)
{
    const float* h    = (const float*)d_in[0];
    const int*   src  = (const int*)d_in[1];
    const int*   dst  = (const int*)d_in[2];
    const float* W1_0 = (const float*)d_in[3];
    const float* b1_0 = (const float*)d_in[4];
    const float* W2_0 = (const float*)d_in[5];
    const float* b2_0 = (const float*)d_in[6];
    const float* g_0  = (const float*)d_in[7];
    const float* be_0 = (const float*)d_in[8];
    const float* W1st = (const float*)d_in[9];
    const float* b1st = (const float*)d_in[10];
    const float* W2st = (const float*)d_in[11];
    const float* b2st = (const float*)d_in[12];
    const float* gst  = (const float*)d_in[13];
    const float* best = (const float*)d_in[14];
    float* out = (float*)d_out;

    float* ws    = (float*)d_ws;
    float* p     = ws;                         // NN*64 floats (projection scratch)
    float* z1    = p + (size_t)NN * 64;        // NN*64 floats (ping-pong)
    float* stats = z1 + (size_t)NN * 64;       // 256 floats
    float* gsum  = stats;
    float* gsq   = stats + 64;
    float* scale = stats + 128;
    float* shift = stats + 192;
    int* off    = (int*)(stats + 256);         // NN+1
    int* deg    = off + (NN + 1);              // NN
    int* cursor = deg + NN;                    // NN
    int* bsum   = cursor + NN;                 // 64
    int* eidx   = bsum + 64;                   // NE

    // ---- CSR build (int atomics only; ~1.6M light atomics total) ----
    hipMemsetAsync(deg, 0, NN * sizeof(int), stream);
    deg_kernel<<<(NE + 255) / 256, 256, 0, stream>>>(dst, deg);
    const int nblk = (NN + 1023) / 1024;
    scan1_kernel<<<nblk, 1024, 0, stream>>>(deg, off, bsum);
    scan2_kernel<<<1, 64, 0, stream>>>(bsum, nblk);
    scan3_kernel<<<(NN + 255) / 256, 256, 0, stream>>>(off, bsum);
    hipMemcpyAsync(cursor, off, NN * sizeof(int), hipMemcpyDeviceToDevice, stream);
    fill_kernel<<<(NE + 255) / 256, 256, 0, stream>>>(src, dst, cursor, eidx);

    const int nodeblk = (NN + 31) / 32;

    auto run_layer = [&](const float* hin, float* zbuf, int D,
                         const float* W1, const float* b1,
                         const float* W2, const float* b2,
                         const float* gamma, const float* beta) {
        hipMemsetAsync(stats, 0, 128 * sizeof(float), stream);
        if (D == 128)
            proj_kernel<128><<<nodeblk, 256, 0, stream>>>(hin, W1, p);
        else
            proj_kernel<64><<<nodeblk, 256, 0, stream>>>(hin, W1, p);
        gmlp_kernel<<<nodeblk, 256, 0, stream>>>(p, off, eidx, b1, W2, b2,
                                                 zbuf, gsum, gsq);
        finalize_kernel<<<1, 64, 0, stream>>>(gsum, gsq, gamma, beta, scale, shift);
        norm_kernel<<<(NN * 16 + 255) / 256, 256, 0, stream>>>(zbuf, scale, shift, zbuf);
    };

    // L0: input h (d=128) -> z1
    run_layer(h, z1, 128, W1_0, b1_0, W2_0, b2_0, g_0, be_0);
    // L1: z1 -> out
    run_layer(z1, out, 64, W1st + 0 * 4096, b1st + 0 * 64, W2st + 0 * 4096,
              b2st + 0 * 64, gst + 0 * 64, best + 0 * 64);
    // L2: out -> z1
    run_layer(out, z1, 64, W1st + 1 * 4096, b1st + 1 * 64, W2st + 1 * 4096,
              b2st + 1 * 64, gst + 1 * 64, best + 1 * 64);
    // L3: z1 -> out (final result lands in d_out)
    run_layer(z1, out, 64, W1st + 2 * 4096, b1st + 2 * 64, W2st + 2 * 4096,
              b2st + 2 * 64, gst + 2 * 64, best + 2 * 64);
}

// Round 3
// 547.490 us; speedup vs baseline: 6.7199x; 1.8352x over previous
//
#include <hip/hip_runtime.h>
#include <hip/hip_bf16.h>

static constexpr int NN = 50000;
static constexpr int NE = 800000;
static constexpr float BN_EPS = 1e-5f;

// ===========================================================================
// CSR build: group edges by dst so aggregation becomes a gather (no fp atomics)
// ===========================================================================
__global__ __launch_bounds__(256) void deg_kernel(const int* __restrict__ dst,
                                                  int* __restrict__ deg)
{
    int e = blockIdx.x * 256 + threadIdx.x;
    if (e < NE) atomicAdd(&deg[dst[e]], 1);
}

__global__ __launch_bounds__(1024) void scan1_kernel(const int* __restrict__ deg,
                                                     int* __restrict__ off,
                                                     int* __restrict__ bsum)
{
    __shared__ int s[1024];
    int t = threadIdx.x;
    int i = blockIdx.x * 1024 + t;
    s[t] = (i < NN) ? deg[i] : 0;
    __syncthreads();
    for (int d = 1; d < 1024; d <<= 1) {
        int x = (t >= d) ? s[t - d] : 0;
        __syncthreads();
        s[t] += x;
        __syncthreads();
    }
    if (i < NN) off[i + 1] = s[t];           // block-local inclusive scan
    if (t == 1023) bsum[blockIdx.x] = s[1023];
}

__global__ void scan2_kernel(int* bsum, int nblk)
{
    if (threadIdx.x == 0 && blockIdx.x == 0) {
        int run = 0;
        for (int i = 0; i < nblk; ++i) { int v = bsum[i]; bsum[i] = run; run += v; }
    }
}

__global__ __launch_bounds__(256) void scan3_kernel(int* __restrict__ off,
                                                    const int* __restrict__ bsum)
{
    int i = blockIdx.x * 256 + threadIdx.x;
    if (i == 0) off[0] = 0;
    if (i < NN) off[i + 1] += bsum[i >> 10];
}

__global__ __launch_bounds__(256) void fill_kernel(const int* __restrict__ src,
                                                   const int* __restrict__ dst,
                                                   int* __restrict__ cursor,
                                                   int* __restrict__ eidx)
{
    int e = blockIdx.x * 256 + threadIdx.x;
    if (e >= NE) return;
    int pos = atomicAdd(&cursor[dst[e]], 1);
    eidx[pos] = src[e];
}

// ===========================================================================
// proj: p = act(hin) @ W1.  act = identity (layer 0) or BN-norm+relu (fused).
// Block = 32 rows, 256 threads; thread computes 2 rows x 4 cols.
// ===========================================================================
template<int D, bool NORM>
__global__ __launch_bounds__(256) void proj_kernel(
    const float* __restrict__ hin, const float* __restrict__ W1,
    const float* __restrict__ scale, const float* __restrict__ shift,
    float* __restrict__ p)
{
    constexpr int ROWS = 32;
    __shared__ float Xs[ROWS][D + 1];
    __shared__ float W1s[D][64];
    __shared__ float scs[NORM ? 64 : 1], shs[NORM ? 64 : 1];

    const int t = threadIdx.x;
    const int rowbase = blockIdx.x * ROWS;

    {
        const float4* w1v = reinterpret_cast<const float4*>(W1);
        float4* w1sv = reinterpret_cast<float4*>(&W1s[0][0]);
        for (int i = t; i < D * 16; i += 256) w1sv[i] = w1v[i];
        if (NORM && t < 64) { scs[t] = scale[t]; shs[t] = shift[t]; }
    }
    if (NORM) __syncthreads();
    {
        constexpr int QPR = D / 4;
        constexpr int RPI = 256 / QPR;
        int q = t % QPR, rr = t / QPR;
        for (int i = 0; i < ROWS; i += RPI) {
            int r = i + rr;
            int gr = rowbase + r;
            float4 v = make_float4(0.f, 0.f, 0.f, 0.f);
            if (gr < NN) {
                v = reinterpret_cast<const float4*>(hin + (size_t)gr * D)[q];
                if (NORM) {
                    int c = q * 4;
                    v.x = fmaxf(v.x * scs[c + 0] + shs[c + 0], 0.f);
                    v.y = fmaxf(v.y * scs[c + 1] + shs[c + 1], 0.f);
                    v.z = fmaxf(v.z * scs[c + 2] + shs[c + 2], 0.f);
                    v.w = fmaxf(v.w * scs[c + 3] + shs[c + 3], 0.f);
                }
            }
            Xs[r][q * 4 + 0] = v.x; Xs[r][q * 4 + 1] = v.y;
            Xs[r][q * 4 + 2] = v.z; Xs[r][q * 4 + 3] = v.w;
        }
    }
    __syncthreads();

    const int tc = t & 15;
    const int tr = t >> 4;
    const int c0 = tc * 4;
    const int r0 = tr * 2;

    float a0x = 0.f, a0y = 0.f, a0z = 0.f, a0w = 0.f;
    float a1x = 0.f, a1y = 0.f, a1z = 0.f, a1w = 0.f;
    for (int k = 0; k < D; ++k) {
        float x0 = Xs[r0][k];
        float x1 = Xs[r0 + 1][k];
        float4 w = *reinterpret_cast<const float4*>(&W1s[k][c0]);
        a0x += x0 * w.x; a0y += x0 * w.y; a0z += x0 * w.z; a0w += x0 * w.w;
        a1x += x1 * w.x; a1y += x1 * w.y; a1z += x1 * w.z; a1w += x1 * w.w;
    }
    int gr0 = rowbase + r0;
    int gr1 = gr0 + 1;
    if (gr0 < NN) reinterpret_cast<float4*>(p + (size_t)gr0 * 64)[tc] =
        make_float4(a0x, a0y, a0z, a0w);
    if (gr1 < NN) reinterpret_cast<float4*>(p + (size_t)gr1 * 64)[tc] =
        make_float4(a1x, a1y, a1z, a1w);
}

// ===========================================================================
// gather: agg[i] = p[i] + sum_{j in N(i)} p[j]
// 16 threads per row (float4 each); edge loop unrolled x4 for MLP.
// ===========================================================================
__global__ __launch_bounds__(256) void gather_kernel(
    const float4* __restrict__ p4, const int* __restrict__ off,
    const int* __restrict__ eidx, float4* __restrict__ agg4)
{
    int gid = blockIdx.x * 256 + threadIdx.x;
    if (gid >= NN * 16) return;
    int row = gid >> 4;
    int q = gid & 15;
    float4 acc = p4[row * 16 + q];
    int e = off[row];
    const int end = off[row + 1];
    for (; e + 4 <= end; e += 4) {
        int s0 = eidx[e + 0], s1 = eidx[e + 1];
        int s2 = eidx[e + 2], s3 = eidx[e + 3];
        float4 v0 = p4[s0 * 16 + q];
        float4 v1 = p4[s1 * 16 + q];
        float4 v2 = p4[s2 * 16 + q];
        float4 v3 = p4[s3 * 16 + q];
        acc.x += (v0.x + v1.x) + (v2.x + v3.x);
        acc.y += (v0.y + v1.y) + (v2.y + v3.y);
        acc.z += (v0.z + v1.z) + (v2.z + v3.z);
        acc.w += (v0.w + v1.w) + (v2.w + v3.w);
    }
    for (; e < end; ++e) {
        int s = eidx[e];
        float4 v = p4[s * 16 + q];
        acc.x += v.x; acc.y += v.y; acc.z += v.z; acc.w += v.w;
    }
    agg4[row * 16 + q] = acc;
}

// ===========================================================================
// mlp2: Y = relu(agg + b1); z = Y @ W2 + b2; accumulate BN stats
// Block = 32 rows, 256 threads.
// ===========================================================================
__global__ __launch_bounds__(256) void mlp2_kernel(
    const float* __restrict__ agg, const float* __restrict__ b1,
    const float* __restrict__ W2, const float* __restrict__ b2,
    float* __restrict__ zout, float* __restrict__ gsum, float* __restrict__ gsq)
{
    constexpr int ROWS = 32;
    __shared__ float Ys[ROWS][65];
    __shared__ float W2s[64][64];
    __shared__ float b1s[64], b2s[64], lsum[64], lsq[64];

    const int t = threadIdx.x;
    const int rowbase = blockIdx.x * ROWS;

    {
        const float4* w2v = reinterpret_cast<const float4*>(W2);
        float4* w2sv = reinterpret_cast<float4*>(&W2s[0][0]);
        for (int i = t; i < 64 * 16; i += 256) w2sv[i] = w2v[i];
        if (t < 64) { b1s[t] = b1[t]; b2s[t] = b2[t]; lsum[t] = 0.f; lsq[t] = 0.f; }
    }
    __syncthreads();

    {
        int q = t & 15;
        int rr = t >> 4;
        for (int i = 0; i < ROWS; i += 16) {
            int r = i + rr;
            int gr = rowbase + r;
            float4 v = make_float4(0.f, 0.f, 0.f, 0.f);
            if (gr < NN) {
                v = reinterpret_cast<const float4*>(agg + (size_t)gr * 64)[q];
                int c = q * 4;
                v.x = fmaxf(v.x + b1s[c + 0], 0.f);
                v.y = fmaxf(v.y + b1s[c + 1], 0.f);
                v.z = fmaxf(v.z + b1s[c + 2], 0.f);
                v.w = fmaxf(v.w + b1s[c + 3], 0.f);
            }
            Ys[r][q * 4 + 0] = v.x; Ys[r][q * 4 + 1] = v.y;
            Ys[r][q * 4 + 2] = v.z; Ys[r][q * 4 + 3] = v.w;
        }
    }
    __syncthreads();

    const int tc = t & 15;
    const int tr = t >> 4;
    const int c0 = tc * 4;
    const int r0 = tr * 2;

    float a0x = 0.f, a0y = 0.f, a0z = 0.f, a0w = 0.f;
    float a1x = 0.f, a1y = 0.f, a1z = 0.f, a1w = 0.f;
    for (int k = 0; k < 64; ++k) {
        float y0 = Ys[r0][k];
        float y1 = Ys[r0 + 1][k];
        float4 w = *reinterpret_cast<const float4*>(&W2s[k][c0]);
        a0x += y0 * w.x; a0y += y0 * w.y; a0z += y0 * w.z; a0w += y0 * w.w;
        a1x += y1 * w.x; a1y += y1 * w.y; a1z += y1 * w.z; a1w += y1 * w.w;
    }
    float z0[4] = { a0x + b2s[c0 + 0], a0y + b2s[c0 + 1],
                    a0z + b2s[c0 + 2], a0w + b2s[c0 + 3] };
    float z1[4] = { a1x + b2s[c0 + 0], a1y + b2s[c0 + 1],
                    a1z + b2s[c0 + 2], a1w + b2s[c0 + 3] };
    int gr0 = rowbase + r0;
    int gr1 = gr0 + 1;
    bool v0 = gr0 < NN, v1 = gr1 < NN;
    if (v0) *reinterpret_cast<float4*>(zout + (size_t)gr0 * 64 + c0) =
        make_float4(z0[0], z0[1], z0[2], z0[3]);
    if (v1) *reinterpret_cast<float4*>(zout + (size_t)gr1 * 64 + c0) =
        make_float4(z1[0], z1[1], z1[2], z1[3]);

    float s[4], q2[4];
    #pragma unroll
    for (int j = 0; j < 4; ++j) {
        float t0 = v0 ? z0[j] : 0.f;
        float t1 = v1 ? z1[j] : 0.f;
        s[j]  = t0 + t1;
        q2[j] = t0 * t0 + t1 * t1;
    }
    #pragma unroll
    for (int j = 0; j < 4; ++j) {
        s[j]  += __shfl_xor(s[j], 16);
        s[j]  += __shfl_xor(s[j], 32);
        q2[j] += __shfl_xor(q2[j], 16);
        q2[j] += __shfl_xor(q2[j], 32);
    }
    if ((t & 48) == 0) {
        #pragma unroll
        for (int j = 0; j < 4; ++j) {
            atomicAdd(&lsum[c0 + j], s[j]);
            atomicAdd(&lsq[c0 + j], q2[j]);
        }
    }
    __syncthreads();
    if (t < 64) {
        atomicAdd(&gsum[t], lsum[t]);
        atomicAdd(&gsq[t], lsq[t]);
    }
}

// ===========================================================================
__global__ void finalize_kernel(const float* __restrict__ gsum,
                                const float* __restrict__ gsq,
                                const float* __restrict__ gamma,
                                const float* __restrict__ beta,
                                float* __restrict__ scale,
                                float* __restrict__ shift)
{
    int c = threadIdx.x;
    if (c >= 64) return;
    const float invn = 1.f / (float)NN;
    float mean = gsum[c] * invn;
    float var  = gsq[c] * invn - mean * mean;
    float inv  = rsqrtf(var + BN_EPS);
    float sc   = gamma[c] * inv;
    scale[c] = sc;
    shift[c] = beta[c] - mean * sc;
}

__global__ __launch_bounds__(256) void norm_kernel(
    const float* __restrict__ z, const float* __restrict__ scale,
    const float* __restrict__ shift, float* __restrict__ out)
{
    __shared__ float sc[64], sh[64];
    if (threadIdx.x < 64) {
        sc[threadIdx.x] = scale[threadIdx.x];
        sh[threadIdx.x] = shift[threadIdx.x];
    }
    __syncthreads();
    int idx = blockIdx.x * 256 + threadIdx.x;   // float4 index
    if (idx >= NN * 16) return;
    int c = (idx & 15) * 4;
    float4 v = reinterpret_cast<const float4*>(z)[idx];
    v.x = fmaxf(v.x * sc[c + 0] + sh[c + 0], 0.f);
    v.y = fmaxf(v.y * sc[c + 1] + sh[c + 1], 0.f);
    v.z = fmaxf(v.z * sc[c + 2] + sh[c + 2], 0.f);
    v.w = fmaxf(v.w * sc[c + 3] + sh[c + 3], 0.f);
    reinterpret_cast<float4*>(out)[idx] = v;
}

// ===========================================================================
extern "C" void kernel_launch(void* const* d_in, const int* in_sizes, int n_in,
                              void* d_out, int out_size, void* d_ws, size_t ws_size,
                              hipStream_t stream)
{
    const float* h    = (const float*)d_in[0];
    const int*   src  = (const int*)d_in[1];
    const int*   dst  = (const int*)d_in[2];
    const float* W1_0 = (const float*)d_in[3];
    const float* b1_0 = (const float*)d_in[4];
    const float* W2_0 = (const float*)d_in[5];
    const float* b2_0 = (const float*)d_in[6];
    const float* g_0  = (const float*)d_in[7];
    const float* be_0 = (const float*)d_in[8];
    const float* W1st = (const float*)d_in[9];
    const float* b1st = (const float*)d_in[10];
    const float* W2st = (const float*)d_in[11];
    const float* b2st = (const float*)d_in[12];
    const float* gst  = (const float*)d_in[13];
    const float* best = (const float*)d_in[14];
    float* out = (float*)d_out;

    float* ws    = (float*)d_ws;
    float* p     = ws;                         // NN*64 (projection)
    float* agg   = p + (size_t)NN * 64;        // NN*64 (aggregated projection)
    float* stats = agg + (size_t)NN * 64;      // 256 floats
    float* gsum  = stats;
    float* gsq   = stats + 64;
    float* scale = stats + 128;
    float* shift = stats + 192;
    int* off    = (int*)(stats + 256);         // NN+1
    int* deg    = off + (NN + 1);              // NN
    int* cursor = deg + NN;                    // NN
    int* bsum   = cursor + NN;                 // 64
    int* eidx   = bsum + 64;                   // NE
    float* z    = out;                         // pre-norm z lives in d_out

    // ---- CSR build (int atomics only) ----
    hipMemsetAsync(deg, 0, NN * sizeof(int), stream);
    deg_kernel<<<(NE + 255) / 256, 256, 0, stream>>>(dst, deg);
    const int nblk = (NN + 1023) / 1024;
    scan1_kernel<<<nblk, 1024, 0, stream>>>(deg, off, bsum);
    scan2_kernel<<<1, 64, 0, stream>>>(bsum, nblk);
    scan3_kernel<<<(NN + 255) / 256, 256, 0, stream>>>(off, bsum);
    hipMemcpyAsync(cursor, off, NN * sizeof(int), hipMemcpyDeviceToDevice, stream);
    fill_kernel<<<(NE + 255) / 256, 256, 0, stream>>>(src, dst, cursor, eidx);

    const int nodeblk = (NN + 31) / 32;
    const int gatherblk = (NN * 16 + 255) / 256;

    auto run_tail = [&](const float* gamma, const float* beta,
                        const float* b1, const float* W2, const float* b2) {
        hipMemsetAsync(stats, 0, 128 * sizeof(float), stream);
        gather_kernel<<<gatherblk, 256, 0, stream>>>(
            (const float4*)p, off, eidx, (float4*)agg);
        mlp2_kernel<<<nodeblk, 256, 0, stream>>>(agg, b1, W2, b2, z, gsum, gsq);
        finalize_kernel<<<1, 64, 0, stream>>>(gsum, gsq, gamma, beta, scale, shift);
    };

    // L0: raw h (D=128), no input norm
    proj_kernel<128, false><<<nodeblk, 256, 0, stream>>>(h, W1_0, scale, shift, p);
    run_tail(g_0, be_0, b1_0, W2_0, b2_0);
    // L1..L3: read pre-norm z from d_out, fuse norm+relu into proj
    for (int l = 0; l < 3; ++l) {
        proj_kernel<64, true><<<nodeblk, 256, 0, stream>>>(
            z, W1st + l * 4096, scale, shift, p);
        run_tail(gst + l * 64, best + l * 64,
                 b1st + l * 64, W2st + l * 4096, b2st + l * 64);
    }
    // final: apply last layer's norm in-place on d_out
    norm_kernel<<<(NN * 16 + 255) / 256, 256, 0, stream>>>(z, scale, shift, out);
}

// Round 4
// 353.122 us; speedup vs baseline: 10.4187x; 1.5504x over previous
//
#include <hip/hip_runtime.h>
#include <hip/hip_bf16.h>

static constexpr int NN = 50000;
static constexpr int NE = 800000;
static constexpr float BN_EPS = 1e-5f;

__device__ __forceinline__ float bflo(unsigned u) { return __uint_as_float(u << 16); }
__device__ __forceinline__ float bfhi(unsigned u) { return __uint_as_float(u & 0xffff0000u); }
__device__ __forceinline__ unsigned short f2bf(float f) {
    unsigned u = __float_as_uint(f);
    unsigned r = (u + 0x7fffu + ((u >> 16) & 1u)) >> 16;
    return (unsigned short)r;
}

// ===========================================================================
// CSR build
// ===========================================================================
__global__ __launch_bounds__(256) void deg_kernel(const int* __restrict__ dst,
                                                  int* __restrict__ deg)
{
    int e = blockIdx.x * 256 + threadIdx.x;
    if (e < NE) atomicAdd(&deg[dst[e]], 1);
}

__global__ __launch_bounds__(1024) void scan1_kernel(const int* __restrict__ deg,
                                                     int* __restrict__ off,
                                                     int* __restrict__ bsum)
{
    __shared__ int s[1024];
    int t = threadIdx.x;
    int i = blockIdx.x * 1024 + t;
    s[t] = (i < NN) ? deg[i] : 0;
    __syncthreads();
    for (int d = 1; d < 1024; d <<= 1) {
        int x = (t >= d) ? s[t - d] : 0;
        __syncthreads();
        s[t] += x;
        __syncthreads();
    }
    if (i < NN) off[i + 1] = s[t];
    if (t == 1023) bsum[blockIdx.x] = s[1023];
}

__global__ void scan2_kernel(int* bsum, int nblk)
{
    if (threadIdx.x == 0 && blockIdx.x == 0) {
        int run = 0;
        for (int i = 0; i < nblk; ++i) { int v = bsum[i]; bsum[i] = run; run += v; }
    }
}

__global__ __launch_bounds__(256) void scan3_kernel(int* __restrict__ off,
                                                    const int* __restrict__ bsum)
{
    int i = blockIdx.x * 256 + threadIdx.x;
    if (i == 0) off[0] = 0;
    if (i < NN) off[i + 1] += bsum[i >> 10];
}

__global__ __launch_bounds__(256) void fill_kernel(const int* __restrict__ src,
                                                   const int* __restrict__ dst,
                                                   int* __restrict__ cursor,
                                                   int* __restrict__ eidx)
{
    int e = blockIdx.x * 256 + threadIdx.x;
    if (e >= NE) return;
    int pos = atomicAdd(&cursor[dst[e]], 1);
    eidx[pos] = src[e];
}

// ===========================================================================
// proj: p(bf16) = act(hin) @ W1.  act = identity or BN(scale/shift)+relu,
// scale/shift computed in-block from gsum/gsq.  128 rows/block, tile 4x8.
// ===========================================================================
template<int D, bool NORM>
__global__ __launch_bounds__(256) void proj_kernel(
    const float* __restrict__ hin, const float* __restrict__ W1,
    const float* __restrict__ gsum, const float* __restrict__ gsq,
    const float* __restrict__ gamma, const float* __restrict__ beta,
    unsigned short* __restrict__ p)
{
    constexpr int RPB = 128;
    __shared__ float XsT[64][132];     // [k][row], pad->conflict-free
    __shared__ float Ws[64][64];
    __shared__ float scs[64], shs[64];

    const int t = threadIdx.x;
    const int rowbase = blockIdx.x * RPB;

    if (NORM) {
        if (t < 64) {
            const float invn = 1.f / (float)NN;
            float mean = gsum[t] * invn;
            float var  = gsq[t] * invn - mean * mean;
            float sc   = gamma[t] * rsqrtf(var + BN_EPS);
            scs[t] = sc;
            shs[t] = beta[t] - mean * sc;
        }
        __syncthreads();
    }

    const int tc = t & 7;        // col group (8 cols)
    const int tr = t >> 3;       // row group (4 rows)
    const int c0 = tc * 8;
    const int r0 = tr * 4;

    float acc[4][8];
    #pragma unroll
    for (int i = 0; i < 4; ++i)
        #pragma unroll
        for (int j = 0; j < 8; ++j) acc[i][j] = 0.f;

    for (int kc = 0; kc < D; kc += 64) {
        if (kc) __syncthreads();
        // stage W chunk (rows kc..kc+63), coalesced float4
        {
            const float4* wg = reinterpret_cast<const float4*>(W1 + (size_t)kc * 64);
            float4* wl = reinterpret_cast<float4*>(&Ws[0][0]);
            for (int i = t; i < 64 * 16; i += 256) wl[i] = wg[i];
        }
        // stage X transposed: rr=t&15 rows, q=t>>4 channel-quads
        {
            int rr = t & 15, q = t >> 4;
            for (int i = 0; i < RPB; i += 16) {
                int r = i + rr;
                int gr = rowbase + r;
                float4 v = make_float4(0.f, 0.f, 0.f, 0.f);
                if (gr < NN) {
                    v = reinterpret_cast<const float4*>(hin + (size_t)gr * D + kc)[q];
                    if (NORM) {
                        int c = q * 4;
                        v.x = fmaxf(v.x * scs[c + 0] + shs[c + 0], 0.f);
                        v.y = fmaxf(v.y * scs[c + 1] + shs[c + 1], 0.f);
                        v.z = fmaxf(v.z * scs[c + 2] + shs[c + 2], 0.f);
                        v.w = fmaxf(v.w * scs[c + 3] + shs[c + 3], 0.f);
                    }
                }
                XsT[q * 4 + 0][r] = v.x;
                XsT[q * 4 + 1][r] = v.y;
                XsT[q * 4 + 2][r] = v.z;
                XsT[q * 4 + 3][r] = v.w;
            }
        }
        __syncthreads();

        for (int k = 0; k < 64; ++k) {
            float4 xa = *reinterpret_cast<const float4*>(&XsT[k][r0]);
            float4 wa = *reinterpret_cast<const float4*>(&Ws[k][c0]);
            float4 wb = *reinterpret_cast<const float4*>(&Ws[k][c0 + 4]);
            float x[4] = { xa.x, xa.y, xa.z, xa.w };
            float w[8] = { wa.x, wa.y, wa.z, wa.w, wb.x, wb.y, wb.z, wb.w };
            #pragma unroll
            for (int i = 0; i < 4; ++i)
                #pragma unroll
                for (int j = 0; j < 8; ++j) acc[i][j] += x[i] * w[j];
        }
    }

    // epilogue: bf16 pack, 16B store per row
    #pragma unroll
    for (int i = 0; i < 4; ++i) {
        int gr = rowbase + r0 + i;
        if (gr < NN) {
            uint4 u;
            u.x = (unsigned)f2bf(acc[i][0]) | ((unsigned)f2bf(acc[i][1]) << 16);
            u.y = (unsigned)f2bf(acc[i][2]) | ((unsigned)f2bf(acc[i][3]) << 16);
            u.z = (unsigned)f2bf(acc[i][4]) | ((unsigned)f2bf(acc[i][5]) << 16);
            u.w = (unsigned)f2bf(acc[i][6]) | ((unsigned)f2bf(acc[i][7]) << 16);
            *reinterpret_cast<uint4*>(p + (size_t)gr * 64 + c0) = u;
        }
    }
}

// ===========================================================================
// gather: Y[i] = relu(p[i] + sum_{j in N(i)} p[j] + b1)   (p bf16 -> Y fp32)
// 16 threads/row, 4 channels (8B bf16) each, edge loop unrolled x4.
// ===========================================================================
__global__ __launch_bounds__(256) void gather_kernel(
    const unsigned short* __restrict__ p, const int* __restrict__ off,
    const int* __restrict__ eidx, const float* __restrict__ b1,
    float* __restrict__ Y)
{
    int gid = blockIdx.x * 256 + threadIdx.x;
    if (gid >= NN * 16) return;
    int row = gid >> 4;
    int q = gid & 15;

    const uint2* pb = reinterpret_cast<const uint2*>(p);
    uint2 u = pb[row * 16 + q];
    float a0 = bflo(u.x), a1 = bfhi(u.x), a2 = bflo(u.y), a3 = bfhi(u.y);

    int e = off[row];
    const int end = off[row + 1];
    for (; e + 4 <= end; e += 4) {
        int s0 = eidx[e + 0], s1 = eidx[e + 1];
        int s2 = eidx[e + 2], s3 = eidx[e + 3];
        uint2 v0 = pb[s0 * 16 + q];
        uint2 v1 = pb[s1 * 16 + q];
        uint2 v2 = pb[s2 * 16 + q];
        uint2 v3 = pb[s3 * 16 + q];
        a0 += (bflo(v0.x) + bflo(v1.x)) + (bflo(v2.x) + bflo(v3.x));
        a1 += (bfhi(v0.x) + bfhi(v1.x)) + (bfhi(v2.x) + bfhi(v3.x));
        a2 += (bflo(v0.y) + bflo(v1.y)) + (bflo(v2.y) + bflo(v3.y));
        a3 += (bfhi(v0.y) + bfhi(v1.y)) + (bfhi(v2.y) + bfhi(v3.y));
    }
    for (; e < end; ++e) {
        uint2 v = pb[eidx[e] * 16 + q];
        a0 += bflo(v.x); a1 += bfhi(v.x); a2 += bflo(v.y); a3 += bfhi(v.y);
    }

    float4 b = reinterpret_cast<const float4*>(b1)[q];
    float4 o;
    o.x = fmaxf(a0 + b.x, 0.f);
    o.y = fmaxf(a1 + b.y, 0.f);
    o.z = fmaxf(a2 + b.z, 0.f);
    o.w = fmaxf(a3 + b.w, 0.f);
    reinterpret_cast<float4*>(Y)[row * 16 + q] = o;
}

// ===========================================================================
// mlp2: z = Y @ W2 + b2 (fp32), store z, accumulate BN stats.
// Same 128-row / 4x8 register tile as proj.
// ===========================================================================
__global__ __launch_bounds__(256) void mlp2_kernel(
    const float* __restrict__ Y, const float* __restrict__ W2,
    const float* __restrict__ b2, float* __restrict__ z,
    float* __restrict__ gsum, float* __restrict__ gsq)
{
    constexpr int RPB = 128;
    __shared__ float XsT[64][132];
    __shared__ float Ws[64][64];
    __shared__ float b2s[64], lsum[64], lsq[64];

    const int t = threadIdx.x;
    const int rowbase = blockIdx.x * RPB;

    if (t < 64) { b2s[t] = b2[t]; lsum[t] = 0.f; lsq[t] = 0.f; }

    {
        const float4* wg = reinterpret_cast<const float4*>(W2);
        float4* wl = reinterpret_cast<float4*>(&Ws[0][0]);
        for (int i = t; i < 64 * 16; i += 256) wl[i] = wg[i];
    }
    {
        int rr = t & 15, q = t >> 4;
        for (int i = 0; i < RPB; i += 16) {
            int r = i + rr;
            int gr = rowbase + r;
            float4 v = make_float4(0.f, 0.f, 0.f, 0.f);
            if (gr < NN)
                v = reinterpret_cast<const float4*>(Y + (size_t)gr * 64)[q];
            XsT[q * 4 + 0][r] = v.x;
            XsT[q * 4 + 1][r] = v.y;
            XsT[q * 4 + 2][r] = v.z;
            XsT[q * 4 + 3][r] = v.w;
        }
    }
    __syncthreads();

    const int tc = t & 7;
    const int tr = t >> 3;
    const int c0 = tc * 8;
    const int r0 = tr * 4;

    float acc[4][8];
    #pragma unroll
    for (int i = 0; i < 4; ++i)
        #pragma unroll
        for (int j = 0; j < 8; ++j) acc[i][j] = 0.f;

    for (int k = 0; k < 64; ++k) {
        float4 xa = *reinterpret_cast<const float4*>(&XsT[k][r0]);
        float4 wa = *reinterpret_cast<const float4*>(&Ws[k][c0]);
        float4 wb = *reinterpret_cast<const float4*>(&Ws[k][c0 + 4]);
        float x[4] = { xa.x, xa.y, xa.z, xa.w };
        float w[8] = { wa.x, wa.y, wa.z, wa.w, wb.x, wb.y, wb.z, wb.w };
        #pragma unroll
        for (int i = 0; i < 4; ++i)
            #pragma unroll
            for (int j = 0; j < 8; ++j) acc[i][j] += x[i] * w[j];
    }

    float s[8], sq[8];
    #pragma unroll
    for (int j = 0; j < 8; ++j) { s[j] = 0.f; sq[j] = 0.f; }

    #pragma unroll
    for (int i = 0; i < 4; ++i) {
        int gr = rowbase + r0 + i;
        if (gr < NN) {
            float zv[8];
            #pragma unroll
            for (int j = 0; j < 8; ++j) {
                zv[j] = acc[i][j] + b2s[c0 + j];
                s[j] += zv[j];
                sq[j] += zv[j] * zv[j];
            }
            float4 lo = make_float4(zv[0], zv[1], zv[2], zv[3]);
            float4 hi = make_float4(zv[4], zv[5], zv[6], zv[7]);
            *reinterpret_cast<float4*>(z + (size_t)gr * 64 + c0) = lo;
            *reinterpret_cast<float4*>(z + (size_t)gr * 64 + c0 + 4) = hi;
        }
    }

    // reduce across the wave's 8 row-groups (lane bits 3..5)
    #pragma unroll
    for (int j = 0; j < 8; ++j) {
        s[j]  += __shfl_xor(s[j], 8);
        s[j]  += __shfl_xor(s[j], 16);
        s[j]  += __shfl_xor(s[j], 32);
        sq[j] += __shfl_xor(sq[j], 8);
        sq[j] += __shfl_xor(sq[j], 16);
        sq[j] += __shfl_xor(sq[j], 32);
    }
    if ((t & 56) == 0) {
        #pragma unroll
        for (int j = 0; j < 8; ++j) {
            atomicAdd(&lsum[c0 + j], s[j]);
            atomicAdd(&lsq[c0 + j], sq[j]);
        }
    }
    __syncthreads();
    if (t < 64) {
        atomicAdd(&gsum[t], lsum[t]);
        atomicAdd(&gsq[t], lsq[t]);
    }
}

// ===========================================================================
// final norm: out = relu(z*scale+shift), scale/shift computed in-block
// ===========================================================================
__global__ __launch_bounds__(256) void norm_kernel(
    const float* __restrict__ z,
    const float* __restrict__ gsum, const float* __restrict__ gsq,
    const float* __restrict__ gamma, const float* __restrict__ beta,
    float* __restrict__ out)
{
    __shared__ float sc[64], sh[64];
    int t = threadIdx.x;
    if (t < 64) {
        const float invn = 1.f / (float)NN;
        float mean = gsum[t] * invn;
        float var  = gsq[t] * invn - mean * mean;
        float s    = gamma[t] * rsqrtf(var + BN_EPS);
        sc[t] = s;
        sh[t] = beta[t] - mean * s;
    }
    __syncthreads();
    int idx = blockIdx.x * 256 + t;
    if (idx >= NN * 16) return;
    int c = (idx & 15) * 4;
    float4 v = reinterpret_cast<const float4*>(z)[idx];
    v.x = fmaxf(v.x * sc[c + 0] + sh[c + 0], 0.f);
    v.y = fmaxf(v.y * sc[c + 1] + sh[c + 1], 0.f);
    v.z = fmaxf(v.z * sc[c + 2] + sh[c + 2], 0.f);
    v.w = fmaxf(v.w * sc[c + 3] + sh[c + 3], 0.f);
    reinterpret_cast<float4*>(out)[idx] = v;
}

// ===========================================================================
extern "C" void kernel_launch(void* const* d_in, const int* in_sizes, int n_in,
                              void* d_out, int out_size, void* d_ws, size_t ws_size,
                              hipStream_t stream)
{
    const float* h    = (const float*)d_in[0];
    const int*   src  = (const int*)d_in[1];
    const int*   dst  = (const int*)d_in[2];
    const float* W1_0 = (const float*)d_in[3];
    const float* b1_0 = (const float*)d_in[4];
    const float* W2_0 = (const float*)d_in[5];
    const float* b2_0 = (const float*)d_in[6];
    const float* g_0  = (const float*)d_in[7];
    const float* be_0 = (const float*)d_in[8];
    const float* W1st = (const float*)d_in[9];
    const float* b1st = (const float*)d_in[10];
    const float* W2st = (const float*)d_in[11];
    const float* b2st = (const float*)d_in[12];
    const float* gst  = (const float*)d_in[13];
    const float* best = (const float*)d_in[14];
    float* out = (float*)d_out;

    char* ws = (char*)d_ws;
    unsigned short* p = (unsigned short*)ws;                 // NN*64 bf16
    float* Y     = (float*)(ws + (size_t)NN * 64 * 2);       // NN*64 fp32
    float* stats = Y + (size_t)NN * 64;                      // 4 layers x 128
    int* off    = (int*)(stats + 512);                       // NN+1
    int* deg    = off + (NN + 1);
    int* cursor = deg + NN;
    int* bsum   = cursor + NN;
    int* eidx   = bsum + 64;                                 // NE
    float* z    = out;                                       // pre-norm z in d_out

    // ---- CSR build ----
    hipMemsetAsync(deg, 0, NN * sizeof(int), stream);
    deg_kernel<<<(NE + 255) / 256, 256, 0, stream>>>(dst, deg);
    const int nblk = (NN + 1023) / 1024;
    scan1_kernel<<<nblk, 1024, 0, stream>>>(deg, off, bsum);
    scan2_kernel<<<1, 64, 0, stream>>>(bsum, nblk);
    scan3_kernel<<<(NN + 255) / 256, 256, 0, stream>>>(off, bsum);
    hipMemcpyAsync(cursor, off, NN * sizeof(int), hipMemcpyDeviceToDevice, stream);
    fill_kernel<<<(NE + 255) / 256, 256, 0, stream>>>(src, dst, cursor, eidx);
    hipMemsetAsync(stats, 0, 512 * sizeof(float), stream);

    const int gemmblk = (NN + 127) / 128;
    const int thrblk  = (NN * 16 + 255) / 256;

    float* gs0 = stats + 0 * 128;      // layer 0 stats
    // L0: h (D=128) -> p -> Y -> z
    proj_kernel<128, false><<<gemmblk, 256, 0, stream>>>(
        h, W1_0, nullptr, nullptr, nullptr, nullptr, p);
    gather_kernel<<<thrblk, 256, 0, stream>>>(p, off, eidx, b1_0, Y);
    mlp2_kernel<<<gemmblk, 256, 0, stream>>>(Y, W2_0, b2_0, z, gs0, gs0 + 64);

    const float* gammas[4] = { g_0, gst + 0, gst + 64, gst + 128 };
    const float* betas[4]  = { be_0, best + 0, best + 64, best + 128 };

    for (int l = 0; l < 3; ++l) {
        float* gsp = stats + l * 128;        // prev layer stats
        float* gsc = stats + (l + 1) * 128;  // this layer stats
        proj_kernel<64, true><<<gemmblk, 256, 0, stream>>>(
            z, W1st + l * 4096, gsp, gsp + 64, gammas[l], betas[l], p);
        gather_kernel<<<thrblk, 256, 0, stream>>>(p, off, eidx, b1st + l * 64, Y);
        mlp2_kernel<<<gemmblk, 256, 0, stream>>>(
            Y, W2st + l * 4096, b2st + l * 64, z, gsc, gsc + 64);
    }

    float* gs3 = stats + 3 * 128;
    norm_kernel<<<thrblk, 256, 0, stream>>>(z, gs3, gs3 + 64, gammas[3], betas[3], out);
}